// Round 19
// baseline (50.859 us; speedup 1.0000x reference)
//
#include <hip/hip_runtime.h>
#include <cmath>

// ROIAlignV2 multi-level FPN pooler. fp32 in/out.
// R19: fused kernel, GC=4 (17.2KB LDS -> 8 blocks/CU = max 32 waves/CU,
// 16384 blocks). Stage window into bf16 LDS tile, pool from LDS, write
// coalesced. No workspace.
constexpr int OUTD = 14;
constexpr int NBIN = OUTD * OUTD;   // 196
constexpr int NS   = 28;            // samples per axis
constexpr int CTOT = 256;           // channels
constexpr int GC   = 4;             // channels per block
constexpr int SLOT = 1088;          // px capacity (worst-case window ~1045)
constexpr int STR  = 6;             // tile row stride in ushorts (12B)

__device__ inline int box_level(const float* __restrict__ boxes, int m,
                                float& bx0, float& by0, float& bx1, float& by1)
{
    bx0 = boxes[m*4+0]; by0 = boxes[m*4+1];
    bx1 = boxes[m*4+2]; by1 = boxes[m*4+3];
    const float size = sqrtf((bx1-bx0)*(by1-by0));
    float lf = floorf(4.0f + log2f(size/224.0f + 2.220446049250313e-16f));
    lf = fminf(fmaxf(lf, 2.0f), 5.0f);
    return (int)lf - 2;             // 0..3
}

__device__ inline void axis_window(float c0, float c1, int HW, int& lo, int& ext)
{
    const float binw = (c1 - c0) * (1.0f/OUTD);
    const float HWm1 = (float)(HW-1);
    const float pL = fminf(fmaxf(c0 + 0.25f*binw, 0.f), HWm1);   // sample 0
    const float pH = fminf(fmaxf(c0 + 13.75f*binw, 0.f), HWm1);  // sample 27
    const int loL = (int)floorf(pL);
    const int hiH = min((int)floorf(pH) + 1, HW - 1);
    lo = loL;
    ext = hiH - loL + 1;
}

__device__ inline float b2f_hi(unsigned int u) {      // high half of packed pair
    return __uint_as_float(u & 0xFFFF0000u);
}
__device__ inline float b2f_lo(unsigned int u) {
    return __uint_as_float(u << 16);
}
__device__ inline unsigned short f2b(float x) {       // RTNE
    unsigned int u = __float_as_uint(x);
    return (unsigned short)((u + 0x7FFFu + ((u >> 16) & 1u)) >> 16);
}

__global__ __launch_bounds__(256) void fused_roi_kernel(
    const float* __restrict__ f0, const float* __restrict__ f1,
    const float* __restrict__ f2, const float* __restrict__ f3,
    const float* __restrict__ boxes, const int* __restrict__ bidx,
    float* __restrict__ out)
{
    const int m   = blockIdx.x;
    const int grp = blockIdx.y;         // 4-channel group, 0..63

    float bx0, by0, bx1, by1;
    const int L = box_level(boxes, m, bx0, by0, bx1, by1);
    const int HW = 256 >> L;
    const float scale = (L==0) ? 0.25f : (L==1) ? 0.125f : (L==2) ? 0.0625f : 0.03125f;
    const float* feat = (L==0) ? f0 : (L==1) ? f1 : (L==2) ? f2 : f3;
    const int b = bidx[m];

    int x0, ww, y0, wh;
    axis_window(bx0*scale - 0.5f, bx1*scale - 0.5f, HW, x0, ww);
    axis_window(by0*scale - 0.5f, by1*scale - 0.5f, HW, y0, wh);
    int area = ww * wh;
    if (area > SLOT) { wh = SLOT / ww; area = ww * wh; }   // safety, never hits

    __shared__ unsigned short tile[SLOT * STR];   // [px][4ch], 12B rows
    __shared__ float obuf[GC * 197];              // [4ch][196bin] padded
    __shared__ int4  s_tab[2][NS];                // window-relative taps

    const int t = threadIdx.x;

    // ---- per-sample tap table (window-relative, validity-folded) ----
    if (t < 2*NS) {
        const int axis = t / NS, s = t % NS;
        const float c0 = (axis ? by0 : bx0) * scale - 0.5f;
        const float c1 = (axis ? by1 : bx1) * scale - 0.5f;
        const float binw = (c1 - c0) * (1.0f/OUTD);
        const float g = (float)(s >> 1) + ((s & 1) ? 0.75f : 0.25f);
        const float p = c0 + g * binw;
        const bool valid = (p > -1.0f) && (p < (float)HW);
        const float pc = fminf(fmaxf(p, 0.0f), (float)(HW - 1));
        int lo = (int)floorf(pc);
        int hi = min(lo + 1, HW - 1);
        const float l = pc - (float)lo;
        const int o = axis ? y0 : x0;
        int4 e; e.x = lo - o; e.y = hi - o;
        e.z = __float_as_int(valid ? (1.0f - l) : 0.0f);
        e.w = __float_as_int(valid ? l : 0.0f);
        s_tab[axis][s] = e;
    }

    // ---- stage window: 4-deep gather per px ----
    const int HWsq = HW * HW;
    const float* cb = feat + (size_t)(b*CTOT + grp*GC) * HWsq;
    for (int c0 = 0; c0 < area; c0 += 256) {
        const int px = c0 + t;
        if (px < area) {
            const int row = px / ww;
            const int g = (y0 + row)*HW + x0 + (px - row*ww);
            float v[GC];
            #pragma unroll
            for (int r = 0; r < GC; ++r) v[r] = cb[(size_t)r*HWsq + g];
            unsigned short* tp = &tile[px * STR];
            #pragma unroll
            for (int r = 0; r < GC; ++r) tp[r] = f2b(v[r]);
        }
    }
    __syncthreads();

    // ---- pool from LDS: item = bin (all 4 ch per thread) ----
    for (int bin = t; bin < NBIN; bin += 256) {
        const int ph = bin / OUTD, pw = bin - ph*OUTD;
        const int4 ty0 = s_tab[1][2*ph], ty1 = s_tab[1][2*ph+1];
        const int4 tx0 = s_tab[0][2*pw], tx1 = s_tab[0][2*pw+1];
        int ro[4]; float wy[4];
        ro[0]=ty0.x*ww; wy[0]=__int_as_float(ty0.z);
        ro[1]=ty0.y*ww; wy[1]=__int_as_float(ty0.w);
        ro[2]=ty1.x*ww; wy[2]=__int_as_float(ty1.z);
        ro[3]=ty1.y*ww; wy[3]=__int_as_float(ty1.w);
        int co[4]; float wx[4];
        co[0]=tx0.x; wx[0]=__int_as_float(tx0.z);
        co[1]=tx0.y; wx[1]=__int_as_float(tx0.w);
        co[2]=tx1.x; wx[2]=__int_as_float(tx1.z);
        co[3]=tx1.y; wx[3]=__int_as_float(tx1.w);

        float a0=0.f, a1=0.f, a2=0.f, a3=0.f;
        #pragma unroll
        for (int k = 0; k < 16; ++k) {
            const int px = ro[k>>2] + co[k&3];
            const float wt = wy[k>>2] * wx[k&3];
            const unsigned int u0 = *(const unsigned int*)&tile[px*STR];
            const unsigned int u1 = *(const unsigned int*)&tile[px*STR + 2];
            a0 = fmaf(wt, b2f_lo(u0), a0);
            a1 = fmaf(wt, b2f_hi(u0), a1);
            a2 = fmaf(wt, b2f_lo(u1), a2);
            a3 = fmaf(wt, b2f_hi(u1), a3);
        }
        float* ob = &obuf[bin];
        ob[0*197] = a0 * 0.25f;
        ob[1*197] = a1 * 0.25f;
        ob[2*197] = a2 * 0.25f;
        ob[3*197] = a3 * 0.25f;
    }
    __syncthreads();

    // ---- coalesced output: out channels [grp*4, grp*4+4) of box m ----
    float* dst = out + ((size_t)m*CTOT + grp*GC) * NBIN;
    for (int j = t; j < GC*NBIN; j += 256) {
        const int ch = j / NBIN;
        dst[j] = obuf[ch*197 + (j - ch*NBIN)];
    }
}

extern "C" void kernel_launch(void* const* d_in, const int* in_sizes, int n_in,
                              void* d_out, int out_size, void* d_ws, size_t ws_size,
                              hipStream_t stream) {
    const float* f0    = (const float*)d_in[0];
    const float* f1    = (const float*)d_in[1];
    const float* f2    = (const float*)d_in[2];
    const float* f3    = (const float*)d_in[3];
    const float* boxes = (const float*)d_in[4];
    const int*   bidx  = (const int*)d_in[5];
    float* out = (float*)d_out;

    const int M = in_sizes[5];
    fused_roi_kernel<<<dim3(M, CTOT/GC), 256, 0, stream>>>(
        f0, f1, f2, f3, boxes, bidx, out);
}

// Round 20
// 46.681 us; speedup vs baseline: 1.0895x; 1.0895x over previous
//
#include <hip/hip_runtime.h>
#include <cmath>

// ROIAlignV2 multi-level FPN pooler. fp32 in/out.
// R20: fused kernel, GC=8, 512-thread blocks (29KB LDS -> 4 blocks/CU x 8
// waves = 32 waves/CU max occupancy; 2-3 serial staging iters). No workspace.
constexpr int OUTD = 14;
constexpr int NBIN = OUTD * OUTD;   // 196
constexpr int NS   = 28;            // samples per axis
constexpr int CTOT = 256;           // channels
constexpr int GC   = 8;             // channels per block
constexpr int NT   = 512;           // threads per block
constexpr int SLOT = 1088;          // px capacity (worst-case window ~1045)
constexpr int STR  = 10;            // tile row stride in ushorts (20B)

__device__ inline int box_level(const float* __restrict__ boxes, int m,
                                float& bx0, float& by0, float& bx1, float& by1)
{
    bx0 = boxes[m*4+0]; by0 = boxes[m*4+1];
    bx1 = boxes[m*4+2]; by1 = boxes[m*4+3];
    const float size = sqrtf((bx1-bx0)*(by1-by0));
    float lf = floorf(4.0f + log2f(size/224.0f + 2.220446049250313e-16f));
    lf = fminf(fmaxf(lf, 2.0f), 5.0f);
    return (int)lf - 2;             // 0..3
}

__device__ inline void axis_window(float c0, float c1, int HW, int& lo, int& ext)
{
    const float binw = (c1 - c0) * (1.0f/OUTD);
    const float HWm1 = (float)(HW-1);
    const float pL = fminf(fmaxf(c0 + 0.25f*binw, 0.f), HWm1);   // sample 0
    const float pH = fminf(fmaxf(c0 + 13.75f*binw, 0.f), HWm1);  // sample 27
    const int loL = (int)floorf(pL);
    const int hiH = min((int)floorf(pH) + 1, HW - 1);
    lo = loL;
    ext = hiH - loL + 1;
}

__device__ inline float b2f_hi(unsigned int u) {      // high half of packed pair
    return __uint_as_float(u & 0xFFFF0000u);
}
__device__ inline float b2f_lo(unsigned int u) {
    return __uint_as_float(u << 16);
}
__device__ inline unsigned short f2b(float x) {       // RTNE
    unsigned int u = __float_as_uint(x);
    return (unsigned short)((u + 0x7FFFu + ((u >> 16) & 1u)) >> 16);
}

__global__ __launch_bounds__(NT) void fused_roi_kernel(
    const float* __restrict__ f0, const float* __restrict__ f1,
    const float* __restrict__ f2, const float* __restrict__ f3,
    const float* __restrict__ boxes, const int* __restrict__ bidx,
    float* __restrict__ out)
{
    const int m   = blockIdx.x;
    const int grp = blockIdx.y;         // 8-channel group, 0..31

    float bx0, by0, bx1, by1;
    const int L = box_level(boxes, m, bx0, by0, bx1, by1);
    const int HW = 256 >> L;
    const float scale = (L==0) ? 0.25f : (L==1) ? 0.125f : (L==2) ? 0.0625f : 0.03125f;
    const float* feat = (L==0) ? f0 : (L==1) ? f1 : (L==2) ? f2 : f3;
    const int b = bidx[m];

    int x0, ww, y0, wh;
    axis_window(bx0*scale - 0.5f, bx1*scale - 0.5f, HW, x0, ww);
    axis_window(by0*scale - 0.5f, by1*scale - 0.5f, HW, y0, wh);
    int area = ww * wh;
    if (area > SLOT) { wh = SLOT / ww; area = ww * wh; }   // safety, never hits

    __shared__ unsigned short tile[SLOT * STR];   // [px][8ch], 20B rows
    __shared__ float obuf[GC * 197];              // [8ch][196bin] padded
    __shared__ int4  s_tab[2][NS];                // window-relative taps

    const int t = threadIdx.x;

    // ---- per-sample tap table (window-relative, validity-folded) ----
    if (t < 2*NS) {
        const int axis = t / NS, s = t % NS;
        const float c0 = (axis ? by0 : bx0) * scale - 0.5f;
        const float c1 = (axis ? by1 : bx1) * scale - 0.5f;
        const float binw = (c1 - c0) * (1.0f/OUTD);
        const float g = (float)(s >> 1) + ((s & 1) ? 0.75f : 0.25f);
        const float p = c0 + g * binw;
        const bool valid = (p > -1.0f) && (p < (float)HW);
        const float pc = fminf(fmaxf(p, 0.0f), (float)(HW - 1));
        int lo = (int)floorf(pc);
        int hi = min(lo + 1, HW - 1);
        const float l = pc - (float)lo;
        const int o = axis ? y0 : x0;
        int4 e; e.x = lo - o; e.y = hi - o;
        e.z = __float_as_int(valid ? (1.0f - l) : 0.0f);
        e.w = __float_as_int(valid ? l : 0.0f);
        s_tab[axis][s] = e;
    }

    // ---- stage window: 8-deep gather per px ----
    const int HWsq = HW * HW;
    const float* cb = feat + (size_t)(b*CTOT + grp*GC) * HWsq;
    for (int c0 = 0; c0 < area; c0 += NT) {
        const int px = c0 + t;
        if (px < area) {
            const int row = px / ww;
            const int g = (y0 + row)*HW + x0 + (px - row*ww);
            float v[GC];
            #pragma unroll
            for (int r = 0; r < GC; ++r) v[r] = cb[(size_t)r*HWsq + g];
            unsigned short* tp = &tile[px * STR];
            #pragma unroll
            for (int r = 0; r < GC; ++r) tp[r] = f2b(v[r]);
        }
    }
    __syncthreads();

    // ---- pool from LDS: item = (bin, 4-ch half) ----
    for (int it = t; it < NBIN*2; it += NT) {
        const int bin = it >> 1, cq = it & 1;
        const int ph = bin / OUTD, pw = bin - ph*OUTD;
        const int4 ty0 = s_tab[1][2*ph], ty1 = s_tab[1][2*ph+1];
        const int4 tx0 = s_tab[0][2*pw], tx1 = s_tab[0][2*pw+1];
        int ro[4]; float wy[4];
        ro[0]=ty0.x*ww; wy[0]=__int_as_float(ty0.z);
        ro[1]=ty0.y*ww; wy[1]=__int_as_float(ty0.w);
        ro[2]=ty1.x*ww; wy[2]=__int_as_float(ty1.z);
        ro[3]=ty1.y*ww; wy[3]=__int_as_float(ty1.w);
        int co[4]; float wx[4];
        co[0]=tx0.x; wx[0]=__int_as_float(tx0.z);
        co[1]=tx0.y; wx[1]=__int_as_float(tx0.w);
        co[2]=tx1.x; wx[2]=__int_as_float(tx1.z);
        co[3]=tx1.y; wx[3]=__int_as_float(tx1.w);

        float a0=0.f, a1=0.f, a2=0.f, a3=0.f;
        #pragma unroll
        for (int k = 0; k < 16; ++k) {
            const int px = ro[k>>2] + co[k&3];
            const float wt = wy[k>>2] * wx[k&3];
            const unsigned int u0 = *(const unsigned int*)&tile[px*STR + 4*cq];
            const unsigned int u1 = *(const unsigned int*)&tile[px*STR + 4*cq + 2];
            a0 = fmaf(wt, b2f_lo(u0), a0);
            a1 = fmaf(wt, b2f_hi(u0), a1);
            a2 = fmaf(wt, b2f_lo(u1), a2);
            a3 = fmaf(wt, b2f_hi(u1), a3);
        }
        float* ob = &obuf[bin];
        ob[(4*cq+0)*197] = a0 * 0.25f;
        ob[(4*cq+1)*197] = a1 * 0.25f;
        ob[(4*cq+2)*197] = a2 * 0.25f;
        ob[(4*cq+3)*197] = a3 * 0.25f;
    }
    __syncthreads();

    // ---- coalesced output: out channels [grp*8, grp*8+8) of box m ----
    float* dst = out + ((size_t)m*CTOT + grp*GC) * NBIN;
    for (int j = t; j < GC*NBIN; j += NT) {
        const int ch = j / NBIN;
        dst[j] = obuf[ch*197 + (j - ch*NBIN)];
    }
}

extern "C" void kernel_launch(void* const* d_in, const int* in_sizes, int n_in,
                              void* d_out, int out_size, void* d_ws, size_t ws_size,
                              hipStream_t stream) {
    const float* f0    = (const float*)d_in[0];
    const float* f1    = (const float*)d_in[1];
    const float* f2    = (const float*)d_in[2];
    const float* f3    = (const float*)d_in[3];
    const float* boxes = (const float*)d_in[4];
    const int*   bidx  = (const int*)d_in[5];
    float* out = (float*)d_out;

    const int M = in_sizes[5];
    fused_roi_kernel<<<dim3(M, CTOT/GC), NT, 0, stream>>>(
        f0, f1, f2, f3, boxes, bidx, out);
}

// Round 21
// 46.405 us; speedup vs baseline: 1.0960x; 1.0060x over previous
//
#include <hip/hip_runtime.h>
#include <cmath>

// ROIAlignV2 multi-level FPN pooler. fp32 in/out.
// R21: R20 + paired-column staging: window padded to even global x (wwe),
// each thread stages 2 px via float2 loads (half the gather instructions).
// GC=8, NT=512, 32 waves/CU. No workspace.
constexpr int OUTD = 14;
constexpr int NBIN = OUTD * OUTD;   // 196
constexpr int NS   = 28;            // samples per axis
constexpr int CTOT = 256;           // channels
constexpr int GC   = 8;             // channels per block
constexpr int NT   = 512;           // threads per block
constexpr int SLOT = 1216;          // padded px capacity (worst ~1152)
constexpr int STR  = 10;            // tile row stride in ushorts (20B)

__device__ inline int box_level(const float* __restrict__ boxes, int m,
                                float& bx0, float& by0, float& bx1, float& by1)
{
    bx0 = boxes[m*4+0]; by0 = boxes[m*4+1];
    bx1 = boxes[m*4+2]; by1 = boxes[m*4+3];
    const float size = sqrtf((bx1-bx0)*(by1-by0));
    float lf = floorf(4.0f + log2f(size/224.0f + 2.220446049250313e-16f));
    lf = fminf(fmaxf(lf, 2.0f), 5.0f);
    return (int)lf - 2;             // 0..3
}

__device__ inline void axis_window(float c0, float c1, int HW, int& lo, int& ext)
{
    const float binw = (c1 - c0) * (1.0f/OUTD);
    const float HWm1 = (float)(HW-1);
    const float pL = fminf(fmaxf(c0 + 0.25f*binw, 0.f), HWm1);   // sample 0
    const float pH = fminf(fmaxf(c0 + 13.75f*binw, 0.f), HWm1);  // sample 27
    const int loL = (int)floorf(pL);
    const int hiH = min((int)floorf(pH) + 1, HW - 1);
    lo = loL;
    ext = hiH - loL + 1;
}

__device__ inline float b2f_hi(unsigned int u) {      // high half of packed pair
    return __uint_as_float(u & 0xFFFF0000u);
}
__device__ inline float b2f_lo(unsigned int u) {
    return __uint_as_float(u << 16);
}
__device__ inline unsigned short f2b(float x) {       // RTNE
    unsigned int u = __float_as_uint(x);
    return (unsigned short)((u + 0x7FFFu + ((u >> 16) & 1u)) >> 16);
}

__global__ __launch_bounds__(NT) void fused_roi_kernel(
    const float* __restrict__ f0, const float* __restrict__ f1,
    const float* __restrict__ f2, const float* __restrict__ f3,
    const float* __restrict__ boxes, const int* __restrict__ bidx,
    float* __restrict__ out)
{
    const int m   = blockIdx.x;
    const int grp = blockIdx.y;         // 8-channel group, 0..31

    float bx0, by0, bx1, by1;
    const int L = box_level(boxes, m, bx0, by0, bx1, by1);
    const int HW = 256 >> L;
    const float scale = (L==0) ? 0.25f : (L==1) ? 0.125f : (L==2) ? 0.0625f : 0.03125f;
    const float* feat = (L==0) ? f0 : (L==1) ? f1 : (L==2) ? f2 : f3;
    const int b = bidx[m];

    int x0, ww, y0, wh;
    axis_window(bx0*scale - 0.5f, bx1*scale - 0.5f, HW, x0, ww);
    axis_window(by0*scale - 0.5f, by1*scale - 0.5f, HW, y0, wh);
    const int x0e = x0 & ~1;                       // even-aligned left edge
    int wwe = ((x0 - x0e) + ww + 1) & ~1;          // even padded width
    if (wwe * wh > SLOT) wh = SLOT / wwe;          // safety, never hits

    __shared__ unsigned short tile[SLOT * STR];    // [px][8ch], 20B rows
    __shared__ float obuf[GC * 197];               // [8ch][196bin] padded
    __shared__ int4  s_tab[2][NS];                 // window-relative taps

    const int t = threadIdx.x;

    // ---- per-sample tap table (relative to x0e / y0, validity-folded) ----
    if (t < 2*NS) {
        const int axis = t / NS, s = t % NS;
        const float c0 = (axis ? by0 : bx0) * scale - 0.5f;
        const float c1 = (axis ? by1 : bx1) * scale - 0.5f;
        const float binw = (c1 - c0) * (1.0f/OUTD);
        const float g = (float)(s >> 1) + ((s & 1) ? 0.75f : 0.25f);
        const float p = c0 + g * binw;
        const bool valid = (p > -1.0f) && (p < (float)HW);
        const float pc = fminf(fmaxf(p, 0.0f), (float)(HW - 1));
        int lo = (int)floorf(pc);
        int hi = min(lo + 1, HW - 1);
        const float l = pc - (float)lo;
        const int o = axis ? y0 : x0e;
        int4 e; e.x = lo - o; e.y = hi - o;
        e.z = __float_as_int(valid ? (1.0f - l) : 0.0f);
        e.w = __float_as_int(valid ? l : 0.0f);
        s_tab[axis][s] = e;
    }

    // ---- stage window: 2 px per thread via float2, 8-deep per px-pair ----
    const int HWsq = HW * HW;
    const float* cb = feat + (size_t)(b*CTOT + grp*GC) * HWsq;
    const int hw2 = wwe >> 1;
    const int items = hw2 * wh;
    for (int c0 = 0; c0 < items; c0 += NT) {
        const int u = c0 + t;
        if (u < items) {
            const int row = u / hw2;
            const int cp  = (u - row*hw2) * 2;
            const int gx  = x0e + cp;
            const int g   = (y0 + row)*HW + gx;
            unsigned short* tp0 = &tile[(row*wwe + cp) * STR];
            unsigned short* tp1 = tp0 + STR;
            if (gx + 1 < HW) {
                float2 v[GC];
                #pragma unroll
                for (int r = 0; r < GC; ++r)
                    v[r] = *(const float2*)(cb + (size_t)r*HWsq + g);
                #pragma unroll
                for (int r = 0; r < GC; ++r) {
                    tp0[r] = f2b(v[r].x);
                    tp1[r] = f2b(v[r].y);
                }
            } else {                                // row-end guard (no OOB)
                float v[GC];
                #pragma unroll
                for (int r = 0; r < GC; ++r) v[r] = cb[(size_t)r*HWsq + g];
                #pragma unroll
                for (int r = 0; r < GC; ++r) tp0[r] = f2b(v[r]);
            }
        }
    }
    __syncthreads();

    // ---- pool from LDS: item = (bin, 4-ch half) ----
    for (int it = t; it < NBIN*2; it += NT) {
        const int bin = it >> 1, cq = it & 1;
        const int ph = bin / OUTD, pw = bin - ph*OUTD;
        const int4 ty0 = s_tab[1][2*ph], ty1 = s_tab[1][2*ph+1];
        const int4 tx0 = s_tab[0][2*pw], tx1 = s_tab[0][2*pw+1];
        int ro[4]; float wy[4];
        ro[0]=ty0.x*wwe; wy[0]=__int_as_float(ty0.z);
        ro[1]=ty0.y*wwe; wy[1]=__int_as_float(ty0.w);
        ro[2]=ty1.x*wwe; wy[2]=__int_as_float(ty1.z);
        ro[3]=ty1.y*wwe; wy[3]=__int_as_float(ty1.w);
        int co[4]; float wx[4];
        co[0]=tx0.x; wx[0]=__int_as_float(tx0.z);
        co[1]=tx0.y; wx[1]=__int_as_float(tx0.w);
        co[2]=tx1.x; wx[2]=__int_as_float(tx1.z);
        co[3]=tx1.y; wx[3]=__int_as_float(tx1.w);

        float a0=0.f, a1=0.f, a2=0.f, a3=0.f;
        #pragma unroll
        for (int k = 0; k < 16; ++k) {
            const int px = ro[k>>2] + co[k&3];
            const float wt = wy[k>>2] * wx[k&3];
            const unsigned int u0 = *(const unsigned int*)&tile[px*STR + 4*cq];
            const unsigned int u1 = *(const unsigned int*)&tile[px*STR + 4*cq + 2];
            a0 = fmaf(wt, b2f_lo(u0), a0);
            a1 = fmaf(wt, b2f_hi(u0), a1);
            a2 = fmaf(wt, b2f_lo(u1), a2);
            a3 = fmaf(wt, b2f_hi(u1), a3);
        }
        float* ob = &obuf[bin];
        ob[(4*cq+0)*197] = a0 * 0.25f;
        ob[(4*cq+1)*197] = a1 * 0.25f;
        ob[(4*cq+2)*197] = a2 * 0.25f;
        ob[(4*cq+3)*197] = a3 * 0.25f;
    }
    __syncthreads();

    // ---- coalesced output: out channels [grp*8, grp*8+8) of box m ----
    float* dst = out + ((size_t)m*CTOT + grp*GC) * NBIN;
    for (int j = t; j < GC*NBIN; j += NT) {
        const int ch = j / NBIN;
        dst[j] = obuf[ch*197 + (j - ch*NBIN)];
    }
}

extern "C" void kernel_launch(void* const* d_in, const int* in_sizes, int n_in,
                              void* d_out, int out_size, void* d_ws, size_t ws_size,
                              hipStream_t stream) {
    const float* f0    = (const float*)d_in[0];
    const float* f1    = (const float*)d_in[1];
    const float* f2    = (const float*)d_in[2];
    const float* f3    = (const float*)d_in[3];
    const float* boxes = (const float*)d_in[4];
    const int*   bidx  = (const int*)d_in[5];
    float* out = (float*)d_out;

    const int M = in_sizes[5];
    fused_roi_kernel<<<dim3(M, CTOT/GC), NT, 0, stream>>>(
        f0, f1, f2, f3, boxes, bidx, out);
}